// Round 8
// baseline (185.274 us; speedup 1.0000x reference)
//
#include <hip/hip_runtime.h>
#include <math.h>

#define T 2048
#define D 512
#define NH 8
#define DH 64
#define NB 4
#define NTOK (NB * T)   // 8192
#define LOG2E 1.44269504f
#define QSCALE (0.125f * LOG2E)

using bf16x8 = __attribute__((ext_vector_type(8))) short;
using f32x4  = __attribute__((ext_vector_type(4))) float;

static __device__ __forceinline__ unsigned short f2bf(float f) {
    union { float f; unsigned u; } v; v.f = f;
    unsigned r = v.u + 0x7fffu + ((v.u >> 16) & 1u);   // RNE
    return (unsigned short)(r >> 16);
}
#if __has_builtin(__builtin_amdgcn_cvt_pk_bf16_f32)
static __device__ __forceinline__ unsigned pack_bf16_pair(float a, float b) {
    auto r = __builtin_amdgcn_cvt_pk_bf16_f32(a, b);
    union { decltype(r) v; unsigned u; } c; c.v = r;
    return c.u;
}
#else
static __device__ __forceinline__ unsigned pack_bf16_pair(float a, float b) {
    union { float f; unsigned u; } ua, ub; ua.f = a; ub.f = b;
    unsigned ra = ua.u + 0x7fffu + ((ua.u >> 16) & 1u);
    unsigned rb = ub.u + 0x7fffu + ((ub.u >> 16) & 1u);
    return __builtin_amdgcn_perm(rb, ra, 0x07060302);
}
#endif

// Fragment layouts (lane = quad*16+lm, 8 bf16 per lane, 1 KB per chunk):
// xfrag  A-frag: chunk = t16*16 + kc           elem = x[t16*16+lm][kc*32+quad*8+e]
// wbfrag B-frag: chunk = j16*16 + kc           elem = W[j16*16+lm][kc*32+quad*8+e]
// qfrag  A-frag: chunk = (bh*128+t16)*2+kk     elem = q[t16*16+lm][kk*32+quad*8+e]
// kfrag  B-frag: chunk = ((bh*32+t64)*2+kk)*4+nt  elem = k[key=t64*64+lm*4+nt][kk*32+quad*8+e]
// vfrag  B-frag: chunk = ((bh*32+t64)*2+kk)*5+nt  elem = v'[dh=nt*16+lm][key=t64*64+kk*32+quad*8+e]
//        (nt=4 column of vfrag = w-vector for l-via-MFMA; v' = w*v)

// ---------------- Kernel 1: fused prep (LN + Wconv + S/cnt-zero) ------------
__global__ __launch_bounds__(256) void prep_kernel(
    const float* __restrict__ embs, const float* __restrict__ labels,
    const float* __restrict__ g, const float* __restrict__ bb,
    const float* __restrict__ alpha_p, const float* __restrict__ beta_p,
    const float* __restrict__ ipw,
    unsigned short* __restrict__ xfrag, float* __restrict__ wexp,
    float* __restrict__ kpmf, unsigned short* __restrict__ wbfrag,
    float* __restrict__ S, int* __restrict__ cnt)
{
    __shared__ __align__(16) unsigned short Sh[16][520];
    int blk = blockIdx.x;
    int tid = threadIdx.x, wave = tid >> 6, lane = tid & 63;
    int quad = lane >> 4, lm = lane & 15;

    if (blk >= 608) {           // ---- S + counter zero (1 block) ----
        float4 z = {0.f, 0.f, 0.f, 0.f};
        ((float4*)S)[tid] = z;
        ((float4*)S)[tid + 256] = z;
        if (tid == 0) *cnt = 0;
        return;
    }

    if (blk < 512) {            // ---- LayerNorm path ----
        int t16 = blk;
        float4 g0 = *(const float4*)(g + lane * 8), g1 = *(const float4*)(g + lane * 8 + 4);
        float4 c0 = *(const float4*)(bb + lane * 8), c1 = *(const float4*)(bb + lane * 8 + 4);
        float gv[8] = {g0.x, g0.y, g0.z, g0.w, g1.x, g1.y, g1.z, g1.w};
        float cv[8] = {c0.x, c0.y, c0.z, c0.w, c1.x, c1.y, c1.z, c1.w};

        for (int tt = 0; tt < 4; ++tt) {
            int n = t16 * 16 + wave * 4 + tt;
            const float* e = embs + (size_t)n * D + lane * 8;
            float4 a4 = *(const float4*)e, b4 = *(const float4*)(e + 4);
            float v[8] = {a4.x, a4.y, a4.z, a4.w, b4.x, b4.y, b4.z, b4.w};

            float s = 0.f, ss = 0.f;
            #pragma unroll
            for (int j = 0; j < 8; ++j) { s += v[j]; ss += v[j] * v[j]; }
            #pragma unroll
            for (int o = 1; o <= 32; o <<= 1) {
                s += __shfl_xor(s, o, 64);
                ss += __shfl_xor(ss, o, 64);
            }
            float mu = s * (1.0f / D);
            float var = ss * (1.0f / D) - mu * mu;
            float rstd = rsqrtf(var + 1e-5f);

            float x[8], as = 0.f;
            #pragma unroll
            for (int j = 0; j < 8; ++j) {
                x[j] = (v[j] - mu) * rstd * gv[j] + cv[j];
                as += fabsf(x[j]);
            }
            uint4 pk;
            pk.x = pack_bf16_pair(x[0], x[1]);
            pk.y = pack_bf16_pair(x[2], x[3]);
            pk.z = pack_bf16_pair(x[4], x[5]);
            pk.w = pack_bf16_pair(x[6], x[7]);
            *(uint4*)&Sh[wave * 4 + tt][lane * 8] = pk;

            #pragma unroll
            for (int o = 1; o <= 32; o <<= 1) as += __shfl_xor(as, o, 64);
            if (lane == 0) {
                int kpm = (as <= 1e-6f);
                kpmf[n] = kpm ? 1.0f : 0.0f;
                wexp[n] = kpm ? 0.0f : __expf(alpha_p[0] * labels[n] + beta_p[0]);
            }
        }
        __syncthreads();
        #pragma unroll
        for (int i = 0; i < 4; ++i) {
            int kc = wave * 4 + i;
            bf16x8 fr = *(const bf16x8*)&Sh[lm][kc * 32 + quad * 8];
            *(bf16x8*)(xfrag + ((size_t)(t16 * 16 + kc) * 64 + lane) * 8) = fr;
        }
    } else {                    // ---- Wconv path ----
        int j16 = blk - 512;
        for (int tt = 0; tt < 4; ++tt) {
            int j = j16 * 16 + wave * 4 + tt;
            const float* wp = ipw + (size_t)j * D + lane * 8;
            float4 a4 = *(const float4*)wp, b4 = *(const float4*)(wp + 4);
            uint4 pk;
            pk.x = pack_bf16_pair(a4.x, a4.y);
            pk.y = pack_bf16_pair(a4.z, a4.w);
            pk.z = pack_bf16_pair(b4.x, b4.y);
            pk.w = pack_bf16_pair(b4.z, b4.w);
            *(uint4*)&Sh[wave * 4 + tt][lane * 8] = pk;
        }
        __syncthreads();
        #pragma unroll
        for (int i = 0; i < 4; ++i) {
            int kc = wave * 4 + i;
            bf16x8 fr = *(const bf16x8*)&Sh[lm][kc * 32 + quad * 8];
            *(bf16x8*)(wbfrag + ((size_t)(j16 * 16 + kc) * 64 + lane) * 8) = fr;
        }
    }
}

// ---------------- Kernel 2: QKV projection, LDS-staged via global_load_lds --
union QkvLds {
    struct { unsigned short A[2][8][512]; unsigned short B[2][8][512]; } st;  // 32 KB
    unsigned short Ls[4][64][72];                                             // 36.9 KB
};
__global__ __launch_bounds__(256) void qkv_mfma(
    const unsigned short* __restrict__ xfrag, const unsigned short* __restrict__ wbfrag,
    const float* __restrict__ bias, const float* __restrict__ wexp,
    unsigned short* __restrict__ qfrag, unsigned short* __restrict__ kfrag,
    unsigned short* __restrict__ vfrag)
{
    __shared__ __align__(16) QkvLds u;
    int tid = threadIdx.x;
    int wave = tid >> 6, lane = tid & 63, quad = lane >> 4, lm = lane & 15;
    int wr = wave >> 1, wc = wave & 1;
    int bx8 = blockIdx.x * 8, by8 = blockIdx.y * 8;
    int m0 = blockIdx.x * 128 + wr * 64;
    int j0 = blockIdx.y * 128 + wc * 64;

    f32x4 acc[4][4];
    #pragma unroll
    for (int a = 0; a < 4; ++a)
        #pragma unroll
        for (int b = 0; b < 4; ++b) acc[a][b] = (f32x4){0.f,0.f,0.f,0.f};

    // wave stages A chunks {2w,2w+1} and B chunks {2w,2w+1} of the kc-slice
    auto stage = [&](int kc, int buf) {
        #pragma unroll
        for (int c = 0; c < 2; ++c) {
            int ci = wave * 2 + c;
            const unsigned short* ga = xfrag + ((size_t)((bx8 + ci) * 16 + kc) * 64 + lane) * 8;
            const unsigned short* gb = wbfrag + ((size_t)((by8 + ci) * 16 + kc) * 64 + lane) * 8;
            __builtin_amdgcn_global_load_lds(
                (const __attribute__((address_space(1))) void*)ga,
                (__attribute__((address_space(3))) void*)&u.st.A[buf][ci][0], 16, 0, 0);
            __builtin_amdgcn_global_load_lds(
                (const __attribute__((address_space(1))) void*)gb,
                (__attribute__((address_space(3))) void*)&u.st.B[buf][ci][0], 16, 0, 0);
        }
    };

    stage(0, 0);
    int buf = 0;
    for (int kc = 0; kc < 16; ++kc) {
        __syncthreads();                      // drains vmcnt -> buf is ready
        if (kc < 15) stage(kc + 1, buf ^ 1);  // async, lands before next barrier
        bf16x8 af[4], bf[4];
        #pragma unroll
        for (int mf = 0; mf < 4; ++mf)
            af[mf] = *(const bf16x8*)&u.st.A[buf][wr * 4 + mf][lane * 8];
        #pragma unroll
        for (int nt = 0; nt < 4; ++nt)
            bf[nt] = *(const bf16x8*)&u.st.B[buf][wc * 4 + nt][lane * 8];
        #pragma unroll
        for (int mf = 0; mf < 4; ++mf)
            #pragma unroll
            for (int nt = 0; nt < 4; ++nt)
                acc[mf][nt] = __builtin_amdgcn_mfma_f32_16x16x32_bf16(af[mf], bf[nt], acc[mf][nt], 0, 0, 0);
        buf ^= 1;
    }
    __syncthreads();   // all staged reads done before epilogue reuses the union

    int part = j0 >> 9;            // 0=q,1=k,2=v
    int h = (j0 & 511) >> 6;
    int b_ = m0 >> 11, tloc = m0 & (T - 1);
    int bh = b_ * NH + h;
    float bcol[4];
    #pragma unroll
    for (int nt = 0; nt < 4; ++nt) bcol[nt] = bias[j0 + nt * 16 + lm];

    if (part == 2) {
        // V' = w*V; LDS [dh][key]; C-layout r-runs contiguous -> b64 writes
        float wv[4][4];
        #pragma unroll
        for (int mf = 0; mf < 4; ++mf)
            #pragma unroll
            for (int r = 0; r < 4; ++r)
                wv[mf][r] = wexp[b_ * T + tloc + mf * 16 + quad * 4 + r];
        #pragma unroll
        for (int mf = 0; mf < 4; ++mf)
            #pragma unroll
            for (int nt = 0; nt < 4; ++nt) {
                uint2 pw;
                pw.x = pack_bf16_pair((acc[mf][nt][0] + bcol[nt]) * wv[mf][0],
                                      (acc[mf][nt][1] + bcol[nt]) * wv[mf][1]);
                pw.y = pack_bf16_pair((acc[mf][nt][2] + bcol[nt]) * wv[mf][2],
                                      (acc[mf][nt][3] + bcol[nt]) * wv[mf][3]);
                *(uint2*)&u.Ls[wave][nt * 16 + lm][mf * 16 + quad * 4] = pw;
            }
        __syncthreads();
        #pragma unroll
        for (int nt = 0; nt < 4; ++nt)
            #pragma unroll
            for (int kk = 0; kk < 2; ++kk) {
                bf16x8 fr = *(const bf16x8*)&u.Ls[wave][nt * 16 + lm][kk * 32 + quad * 8];
                size_t chunk = ((((size_t)bh * 32 + (tloc >> 6)) * 2 + kk) * 5) + nt;
                *(bf16x8*)(vfrag + chunk * 512 + lane * 8) = fr;
            }
        // w-column (nt=4) of vfrag: lm==0 lanes carry w, rest zero.
        #pragma unroll
        for (int kk = 0; kk < 2; ++kk) {
            size_t chunk = ((((size_t)bh * 32 + (tloc >> 6)) * 2 + kk) * 5) + 4;
            uint4 pk = {0u, 0u, 0u, 0u};
            if (lm == 0) {
                const float* wp = wexp + b_ * T + tloc + kk * 32 + quad * 8;
                unsigned short vv[8];
                #pragma unroll
                for (int e = 0; e < 8; ++e) vv[e] = f2bf(wp[e]);
                pk = *(uint4*)vv;
            }
            *(uint4*)(vfrag + chunk * 512 + (size_t)lane * 8) = pk;
        }
    } else {
        // LDS [token][dh]; scalar b16 writes (one-time), b128 frag reads
        float scale = (part == 0) ? QSCALE : 1.0f;
        #pragma unroll
        for (int mf = 0; mf < 4; ++mf)
            #pragma unroll
            for (int nt = 0; nt < 4; ++nt)
                #pragma unroll
                for (int r = 0; r < 4; ++r)
                    u.Ls[wave][mf * 16 + quad * 4 + r][nt * 16 + lm] =
                        f2bf((acc[mf][nt][r] + bcol[nt]) * scale);
        __syncthreads();
        if (part == 0) {
            #pragma unroll
            for (int mf = 0; mf < 4; ++mf)
                #pragma unroll
                for (int kk = 0; kk < 2; ++kk) {
                    bf16x8 fr = *(const bf16x8*)&u.Ls[wave][mf * 16 + lm][kk * 32 + quad * 8];
                    size_t chunk = ((size_t)bh * 128 + (tloc >> 4) + mf) * 2 + kk;
                    *(bf16x8*)(qfrag + chunk * 512 + lane * 8) = fr;
                }
        } else {
            #pragma unroll
            for (int nta = 0; nta < 4; ++nta)
                #pragma unroll
                for (int kk = 0; kk < 2; ++kk) {
                    bf16x8 fr = *(const bf16x8*)&u.Ls[wave][lm * 4 + nta][kk * 32 + quad * 8];
                    size_t chunk = ((((size_t)bh * 32 + (tloc >> 6)) * 2 + kk) * 4) + nta;
                    *(bf16x8*)(kfrag + chunk * 512 + lane * 8) = fr;
                }
        }
    }
}

// ---------------- Kernel 3: flash attention + fused out-projection ----------
// Attn loop unchanged from R3/R4 (48.8us proven). New tail: each block does a
// device-scope arrival after its S atomics; blocks g<32 spin until all 512
// arrived (deadlock-free: waiters <=32 slots, no circular wait; and all 512
// are co-resident at 2/CU anyway), then run the out-projection in-kernel.
// Saves the out_kernel launch + one drain boundary. S read back with
// agent-scope atomic loads (bypass possibly-stale L1 across XCDs).
union AttnU {
    struct { unsigned short Ps[4][2][64][72]; float Lx[2][2][64]; } a;  // 74752 B
    struct { float Sl[512]; float cs[4]; float pr[4][64]; } o;          // 3.1 KB
};
__global__ __launch_bounds__(256, 2) void attn_mfma(
    const unsigned short* __restrict__ qfrag, const unsigned short* __restrict__ kfrag,
    const unsigned short* __restrict__ vfrag, const float* __restrict__ kpmf,
    float* S, int* cnt,
    const float* __restrict__ Wo, const float* __restrict__ bo,
    float* __restrict__ out)
{
    __shared__ __align__(16) AttnU u;
    int gidx = blockIdx.x;
    int bh = gidx & 31, q0 = (gidx >> 5) * 128;
    int tid = threadIdx.x, wave = tid >> 6, lane = tid & 63;
    int quad = lane >> 4, lm = lane & 15;
    int qh = wave >> 1, ks = wave & 1;
    int qbase = q0 + qh * 64;
    int b_ = bh >> 3, h = bh & 7;

    bf16x8 qf[4][2];
    int t16b = (qbase >> 4);
    #pragma unroll
    for (int mf = 0; mf < 4; ++mf)
        #pragma unroll
        for (int kk = 0; kk < 2; ++kk)
            qf[mf][kk] = *(const bf16x8*)(qfrag +
                (((size_t)(bh * 128 + t16b + mf) * 2 + kk) * 64 + lane) * 8);

    f32x4 accO[4][4], accL[4];
    #pragma unroll
    for (int mf = 0; mf < 4; ++mf) {
        #pragma unroll
        for (int nt = 0; nt < 4; ++nt) accO[mf][nt] = (f32x4){0.f,0.f,0.f,0.f};
        accL[mf] = (f32x4){0.f,0.f,0.f,0.f};
    }

    const unsigned short* kb = kfrag + (size_t)bh * 32 * 8 * 512 + (size_t)lane * 8;
    const unsigned short* vb = vfrag + (size_t)bh * 32 * 10 * 512 + (size_t)lane * 8;
    int t0k = ks * 16;   // wave's 16 key-tiles

    bf16x8 kf[4][2];
    auto load_k = [&](int t64) {
        const unsigned short* p = kb + (size_t)t64 * 8 * 512;
        #pragma unroll
        for (int kk = 0; kk < 2; ++kk)
            #pragma unroll
            for (int nt = 0; nt < 4; ++nt)
                kf[nt][kk] = *(const bf16x8*)(p + ((size_t)kk * 4 + nt) * 512);
    };
    auto load_v = [&](int t64, bf16x8 (&vf)[5][2]) {
        const unsigned short* p = vb + (size_t)t64 * 10 * 512;
        #pragma unroll
        for (int kk = 0; kk < 2; ++kk)
            #pragma unroll
            for (int nt = 0; nt < 5; ++nt)
                vf[nt][kk] = *(const bf16x8*)(p + ((size_t)kk * 5 + nt) * 512);
    };
    auto load_p = [&](int buf, bf16x8 (&pf)[4][2]) {
        #pragma unroll
        for (int mf = 0; mf < 4; ++mf)
            #pragma unroll
            for (int kk = 0; kk < 2; ++kk)
                pf[mf][kk] = *(const bf16x8*)&u.a.Ps[wave][buf][mf * 16 + lm][kk * 32 + quad * 8];
    };
    // QK(current kf) -> exp2 -> write Ps[buf]
    auto qk_exp = [&](int buf) {
        #pragma unroll
        for (int mf = 0; mf < 4; ++mf) {
            f32x4 s[4];
            __builtin_amdgcn_s_setprio(1);
            #pragma unroll
            for (int nt = 0; nt < 4; ++nt) {
                f32x4 t0 = (f32x4){0.f,0.f,0.f,0.f};
                t0 = __builtin_amdgcn_mfma_f32_16x16x32_bf16(qf[mf][0], kf[nt][0], t0, 0, 0, 0);
                t0 = __builtin_amdgcn_mfma_f32_16x16x32_bf16(qf[mf][1], kf[nt][1], t0, 0, 0, 0);
                s[nt] = t0;
            }
            __builtin_amdgcn_s_setprio(0);
            int rowb = mf * 16 + quad * 4;
            #pragma unroll
            for (int r = 0; r < 4; ++r) {
                float p0 = __builtin_amdgcn_exp2f(s[0][r]);
                float p1 = __builtin_amdgcn_exp2f(s[1][r]);
                float p2 = __builtin_amdgcn_exp2f(s[2][r]);
                float p3 = __builtin_amdgcn_exp2f(s[3][r]);
                uint2 pw;
                pw.x = pack_bf16_pair(p0, p1);
                pw.y = pack_bf16_pair(p2, p3);
                *(uint2*)&u.a.Ps[wave][buf][rowb + r][lm * 4] = pw;
            }
        }
    };
    auto pv = [&](bf16x8 (&pf)[4][2], bf16x8 (&vf)[5][2]) {
        __builtin_amdgcn_s_setprio(1);
        #pragma unroll
        for (int mf = 0; mf < 4; ++mf) {
            #pragma unroll
            for (int nt = 0; nt < 4; ++nt) {
                accO[mf][nt] = __builtin_amdgcn_mfma_f32_16x16x32_bf16(pf[mf][0], vf[nt][0], accO[mf][nt], 0, 0, 0);
                accO[mf][nt] = __builtin_amdgcn_mfma_f32_16x16x32_bf16(pf[mf][1], vf[nt][1], accO[mf][nt], 0, 0, 0);
            }
            accL[mf] = __builtin_amdgcn_mfma_f32_16x16x32_bf16(pf[mf][0], vf[4][0], accL[mf], 0, 0, 0);
            accL[mf] = __builtin_amdgcn_mfma_f32_16x16x32_bf16(pf[mf][1], vf[4][1], accL[mf], 0, 0, 0);
        }
        __builtin_amdgcn_s_setprio(0);
    };

    // software pipeline, one tile deep: PV(t-1) overlaps QK/exp(t)
    load_k(t0k);
    qk_exp(0);                       // tile 0 -> Ps buf 0
    load_k(t0k + 1);
    for (int t = 1; t < 16; ++t) {
        bf16x8 pf[4][2], vf[5][2];
        load_p((t - 1) & 1, pf);     // LDS latency hides under QK(t)
        load_v(t0k + t - 1, vf);     // L2 latency hides under QK+exp(t)
        qk_exp(t & 1);
        load_k(t0k + ((t + 1) & 15));  // phantom wrap reload on last iter
        pv(pf, vf);
    }
    {   // epilogue: PV of tile 15
        bf16x8 pf[4][2], vf[5][2];
        load_p(1, pf);
        load_v(t0k + 15, vf);
        pv(pf, vf);
    }

    // exchange partial l across the key-half pair (one barrier total)
    if (lm == 0) {
        #pragma unroll
        for (int mf = 0; mf < 4; ++mf)
            #pragma unroll
            for (int r = 0; r < 4; ++r)
                u.a.Lx[qh][ks][mf * 16 + quad * 4 + r] = accL[mf][r];
    }
    __syncthreads();

    // fused masked pooling with full l
    float pooled[4] = {0.f, 0.f, 0.f, 0.f};
    #pragma unroll
    for (int mf = 0; mf < 4; ++mf)
        #pragma unroll
        for (int r = 0; r < 4; ++r) {
            int rloc = mf * 16 + quad * 4 + r;
            float l = u.a.Lx[qh][0][rloc] + u.a.Lx[qh][1][rloc];
            float w = (1.0f - kpmf[b_ * T + qbase + rloc]) / l;
            #pragma unroll
            for (int nt = 0; nt < 4; ++nt) pooled[nt] += accO[mf][nt][r] * w;
        }
    #pragma unroll
    for (int nt = 0; nt < 4; ++nt) {
        pooled[nt] += __shfl_xor(pooled[nt], 16, 64);
        pooled[nt] += __shfl_xor(pooled[nt], 32, 64);
    }
    if (quad == 0) {
        #pragma unroll
        for (int nt = 0; nt < 4; ++nt)
            atomicAdd(&S[b_ * D + h * DH + nt * 16 + lm], pooled[nt]);
    }

    // -------- fused out-projection tail --------
    __syncthreads();
    __threadfence();                               // release: S atomics visible
    if (tid == 0)
        __hip_atomic_fetch_add(cnt, 1, __ATOMIC_ACQ_REL, __HIP_MEMORY_SCOPE_AGENT);
    if (gidx >= 32) return;

    if (tid == 0) {
        while (__hip_atomic_load(cnt, __ATOMIC_ACQUIRE, __HIP_MEMORY_SCOPE_AGENT) < 512)
            __builtin_amdgcn_s_sleep(8);
    }
    __syncthreads();                               // all threads see completion
    {
        int ob = gidx >> 3;                        // batch
        int cg = gidx & 7;                         // 64-col group
        int col = tid & 63, kq = tid >> 6;
        // agent-scope atomic loads: bypass stale L1 (S written by other XCDs)
        u.o.Sl[tid] = __hip_atomic_load(&S[ob * D + tid], __ATOMIC_RELAXED,
                                        __HIP_MEMORY_SCOPE_AGENT);
        u.o.Sl[tid + 256] = __hip_atomic_load(&S[ob * D + tid + 256], __ATOMIC_RELAXED,
                                              __HIP_MEMORY_SCOPE_AGENT);
        const float* kp = kpmf + ob * T;
        float c = 0.f;
        for (int t = tid; t < T; t += 256) c += kp[t];
        #pragma unroll
        for (int o = 32; o; o >>= 1) c += __shfl_xor(c, o, 64);
        if ((tid & 63) == 0) u.o.cs[tid >> 6] = c;
        __syncthreads();
        float masked = u.o.cs[0] + u.o.cs[1] + u.o.cs[2] + u.o.cs[3];
        float cnt_ = (float)T - masked;
        float inv = 1.0f / fmaxf(cnt_, 1.0f);

        int d = cg * 64 + col;
        const float4* wr4 = (const float4*)(Wo + (size_t)d * D + kq * 128);
        float dot = 0.f;
        #pragma unroll 8
        for (int i = 0; i < 32; ++i) {
            float4 w4 = wr4[i];
            int kbase = kq * 128 + i * 4;
            dot += u.o.Sl[kbase + 0] * w4.x + u.o.Sl[kbase + 1] * w4.y +
                   u.o.Sl[kbase + 2] * w4.z + u.o.Sl[kbase + 3] * w4.w;
        }
        u.o.pr[kq][col] = dot;
        __syncthreads();
        if (kq == 0) {
            float tot = u.o.pr[0][col] + u.o.pr[1][col] + u.o.pr[2][col] + u.o.pr[3][col];
            out[ob * D + d] = (tot + bo[d] * cnt_) * inv;
        }
    }
}

extern "C" void kernel_launch(void* const* d_in, const int* in_sizes, int n_in,
                              void* d_out, int out_size, void* d_ws, size_t ws_size,
                              hipStream_t stream) {
    const float* embs   = (const float*)d_in[0];
    const float* labels = (const float*)d_in[1];
    const float* ln_g   = (const float*)d_in[2];
    const float* ln_b   = (const float*)d_in[3];
    const float* ipw    = (const float*)d_in[4];
    const float* ipb    = (const float*)d_in[5];
    const float* ow     = (const float*)d_in[6];
    const float* obb    = (const float*)d_in[7];
    const float* alpha  = (const float*)d_in[8];
    const float* beta   = (const float*)d_in[9];
    float* out = (float*)d_out;

    unsigned short* xfrag  = (unsigned short*)d_ws;          // 8192*512
    unsigned short* wbfrag = xfrag + (size_t)NTOK * D;       // 1536*512
    unsigned short* qfrag  = wbfrag + (size_t)3 * D * D;     // 8192*512
    unsigned short* kfrag  = qfrag + (size_t)NTOK * D;       // 8192*512
    unsigned short* vfrag  = kfrag + (size_t)NTOK * D;       // 32*32*2*5*512
    float* wexp = (float*)(vfrag + (size_t)32 * 32 * 2 * 5 * 512);  // 8192
    float* kpmf = wexp + NTOK;                               // 8192
    float* S    = kpmf + NTOK;                               // 2048
    int*   cnt  = (int*)(S + NB * D);                        // 1 int

    prep_kernel<<<609, 256, 0, stream>>>(embs, labels, ln_g, ln_b, alpha, beta,
                                         ipw, xfrag, wexp, kpmf, wbfrag, S, cnt);
    dim3 gq(NTOK / 128, (3 * D) / 128);
    qkv_mfma<<<gq, 256, 0, stream>>>(xfrag, wbfrag, ipb, wexp, qfrag, kfrag, vfrag);
    attn_mfma<<<32 * (T / 128), 256, 0, stream>>>(qfrag, kfrag, vfrag, kpmf,
                                                  S, cnt, ow, obb, out);
}

// Round 9
// 150.854 us; speedup vs baseline: 1.2282x; 1.2282x over previous
//
#include <hip/hip_runtime.h>
#include <math.h>

#define T 2048
#define D 512
#define NH 8
#define DH 64
#define NB 4
#define NTOK (NB * T)   // 8192
#define LOG2E 1.44269504f
#define QSCALE (0.125f * LOG2E)

using bf16x8 = __attribute__((ext_vector_type(8))) short;
using f32x4  = __attribute__((ext_vector_type(4))) float;

static __device__ __forceinline__ unsigned short f2bf(float f) {
    union { float f; unsigned u; } v; v.f = f;
    unsigned r = v.u + 0x7fffu + ((v.u >> 16) & 1u);   // RNE
    return (unsigned short)(r >> 16);
}
#if __has_builtin(__builtin_amdgcn_cvt_pk_bf16_f32)
static __device__ __forceinline__ unsigned pack_bf16_pair(float a, float b) {
    auto r = __builtin_amdgcn_cvt_pk_bf16_f32(a, b);
    union { decltype(r) v; unsigned u; } c; c.v = r;
    return c.u;
}
#else
static __device__ __forceinline__ unsigned pack_bf16_pair(float a, float b) {
    union { float f; unsigned u; } ua, ub; ua.f = a; ub.f = b;
    unsigned ra = ua.u + 0x7fffu + ((ua.u >> 16) & 1u);
    unsigned rb = ub.u + 0x7fffu + ((ub.u >> 16) & 1u);
    return __builtin_amdgcn_perm(rb, ra, 0x07060302);
}
#endif

// Fragment layouts (lane = quad*16+lm, 8 bf16 per lane, 1 KB per chunk):
// xfrag  A-frag: chunk = t16*16 + kc           elem = x[t16*16+lm][kc*32+quad*8+e]
// wbfrag B-frag: chunk = j16*16 + kc           elem = W[j16*16+lm][kc*32+quad*8+e]
// qfrag  A-frag: chunk = (bh*128+t16)*2+kk     elem = q[t16*16+lm][kk*32+quad*8+e]
// kfrag  B-frag: chunk = ((bh*32+t64)*2+kk)*4+nt  elem = k[key=t64*64+lm*4+nt][kk*32+quad*8+e]
// vfrag  B-frag: chunk = ((bh*32+t64)*2+kk)*5+nt  elem = v'[dh=nt*16+lm][key=t64*64+kk*32+quad*8+e]
//        (nt=4 column of vfrag = w-vector for l-via-MFMA; v' = w*v)
//
// SESSION LEDGER (why this is the final configuration):
//  R3: P-dbuf software pipeline in attn  -> attn 53->49us (real win)
//  R4: prep fusion + wfrag fold          -> total 157->150.3us (real win)
//  R1/R2: occupancy attempts             -> register-locked at 2 waves/SIMD
//         (acc 80 + working set ~200 regs; occupancy steps at 128/256)
//  R5 XCD remap / R7 LDS-staged qkv      -> neutral (+-2us noise band)
//  R6 mega-kernel                        -> spills (one VGPR budget per kernel)
//  R8 cooperative out-fusion             -> per-block device-fence tax ~45us
//  R6 also measured ~60us fixed harness overhead (single 465us dispatch ->
//  526us bench), so GPU work here is ~90us: attn 48 + qkv ~18 + prep ~9 +
//  out ~3 + boundaries ~7.

// ---------------- Kernel 1: fused prep (LN + Wconv + S-zero) ----------------
__global__ __launch_bounds__(256) void prep_kernel(
    const float* __restrict__ embs, const float* __restrict__ labels,
    const float* __restrict__ g, const float* __restrict__ bb,
    const float* __restrict__ alpha_p, const float* __restrict__ beta_p,
    const float* __restrict__ ipw,
    unsigned short* __restrict__ xfrag, float* __restrict__ wexp,
    float* __restrict__ kpmf, unsigned short* __restrict__ wbfrag,
    float* __restrict__ S)
{
    __shared__ __align__(16) unsigned short Sh[16][520];
    int blk = blockIdx.x;
    int tid = threadIdx.x, wave = tid >> 6, lane = tid & 63;
    int quad = lane >> 4, lm = lane & 15;

    if (blk >= 608) {           // ---- S zero (1 block) ----
        float4 z = {0.f, 0.f, 0.f, 0.f};
        ((float4*)S)[tid] = z;
        ((float4*)S)[tid + 256] = z;
        return;
    }

    if (blk < 512) {            // ---- LayerNorm path ----
        int t16 = blk;
        float4 g0 = *(const float4*)(g + lane * 8), g1 = *(const float4*)(g + lane * 8 + 4);
        float4 c0 = *(const float4*)(bb + lane * 8), c1 = *(const float4*)(bb + lane * 8 + 4);
        float gv[8] = {g0.x, g0.y, g0.z, g0.w, g1.x, g1.y, g1.z, g1.w};
        float cv[8] = {c0.x, c0.y, c0.z, c0.w, c1.x, c1.y, c1.z, c1.w};

        for (int tt = 0; tt < 4; ++tt) {
            int n = t16 * 16 + wave * 4 + tt;
            const float* e = embs + (size_t)n * D + lane * 8;
            float4 a4 = *(const float4*)e, b4 = *(const float4*)(e + 4);
            float v[8] = {a4.x, a4.y, a4.z, a4.w, b4.x, b4.y, b4.z, b4.w};

            float s = 0.f, ss = 0.f;
            #pragma unroll
            for (int j = 0; j < 8; ++j) { s += v[j]; ss += v[j] * v[j]; }
            #pragma unroll
            for (int o = 1; o <= 32; o <<= 1) {
                s += __shfl_xor(s, o, 64);
                ss += __shfl_xor(ss, o, 64);
            }
            float mu = s * (1.0f / D);
            float var = ss * (1.0f / D) - mu * mu;
            float rstd = rsqrtf(var + 1e-5f);

            float x[8], as = 0.f;
            #pragma unroll
            for (int j = 0; j < 8; ++j) {
                x[j] = (v[j] - mu) * rstd * gv[j] + cv[j];
                as += fabsf(x[j]);
            }
            uint4 pk;
            pk.x = pack_bf16_pair(x[0], x[1]);
            pk.y = pack_bf16_pair(x[2], x[3]);
            pk.z = pack_bf16_pair(x[4], x[5]);
            pk.w = pack_bf16_pair(x[6], x[7]);
            *(uint4*)&Sh[wave * 4 + tt][lane * 8] = pk;

            #pragma unroll
            for (int o = 1; o <= 32; o <<= 1) as += __shfl_xor(as, o, 64);
            if (lane == 0) {
                int kpm = (as <= 1e-6f);
                kpmf[n] = kpm ? 1.0f : 0.0f;
                wexp[n] = kpm ? 0.0f : __expf(alpha_p[0] * labels[n] + beta_p[0]);
            }
        }
        __syncthreads();
        #pragma unroll
        for (int i = 0; i < 4; ++i) {
            int kc = wave * 4 + i;
            bf16x8 fr = *(const bf16x8*)&Sh[lm][kc * 32 + quad * 8];
            *(bf16x8*)(xfrag + ((size_t)(t16 * 16 + kc) * 64 + lane) * 8) = fr;
        }
    } else {                    // ---- Wconv path ----
        int j16 = blk - 512;
        for (int tt = 0; tt < 4; ++tt) {
            int j = j16 * 16 + wave * 4 + tt;
            const float* wp = ipw + (size_t)j * D + lane * 8;
            float4 a4 = *(const float4*)wp, b4 = *(const float4*)(wp + 4);
            uint4 pk;
            pk.x = pack_bf16_pair(a4.x, a4.y);
            pk.y = pack_bf16_pair(a4.z, a4.w);
            pk.z = pack_bf16_pair(b4.x, b4.y);
            pk.w = pack_bf16_pair(b4.z, b4.w);
            *(uint4*)&Sh[wave * 4 + tt][lane * 8] = pk;
        }
        __syncthreads();
        #pragma unroll
        for (int i = 0; i < 4; ++i) {
            int kc = wave * 4 + i;
            bf16x8 fr = *(const bf16x8*)&Sh[lm][kc * 32 + quad * 8];
            *(bf16x8*)(wbfrag + ((size_t)(j16 * 16 + kc) * 64 + lane) * 8) = fr;
        }
    }
}

// ---------------- Kernel 2: QKV projection + vfrag w-column fill ------------
__global__ __launch_bounds__(256) void qkv_mfma(
    const unsigned short* __restrict__ xfrag, const unsigned short* __restrict__ wbfrag,
    const float* __restrict__ bias, const float* __restrict__ wexp,
    unsigned short* __restrict__ qfrag, unsigned short* __restrict__ kfrag,
    unsigned short* __restrict__ vfrag)
{
    __shared__ __align__(16) unsigned short Ls[4][64][72];
    int tid = threadIdx.x;
    int wave = tid >> 6, lane = tid & 63, quad = lane >> 4, lm = lane & 15;
    int wr = wave >> 1, wc = wave & 1;
    int m0 = blockIdx.x * 128 + wr * 64;
    int j0 = blockIdx.y * 128 + wc * 64;
    int mt16 = m0 >> 4, jt16 = j0 >> 4;

    f32x4 acc[4][4];
    #pragma unroll
    for (int a = 0; a < 4; ++a)
        #pragma unroll
        for (int b = 0; b < 4; ++b) acc[a][b] = (f32x4){0.f,0.f,0.f,0.f};

    bf16x8 af0[4], bf0[4], af1[4], bf1[4];
    auto load_ab = [&](int kc, bf16x8 (&af)[4], bf16x8 (&bf)[4]) {
        #pragma unroll
        for (int mf = 0; mf < 4; ++mf)
            af[mf] = *(const bf16x8*)(xfrag + ((size_t)((mt16 + mf) * 16 + kc) * 64 + lane) * 8);
        #pragma unroll
        for (int nt = 0; nt < 4; ++nt)
            bf[nt] = *(const bf16x8*)(wbfrag + ((size_t)((jt16 + nt) * 16 + kc) * 64 + lane) * 8);
    };
    auto do_mfma = [&](bf16x8 (&af)[4], bf16x8 (&bf)[4]) {
        #pragma unroll
        for (int mf = 0; mf < 4; ++mf)
            #pragma unroll
            for (int nt = 0; nt < 4; ++nt)
                acc[mf][nt] = __builtin_amdgcn_mfma_f32_16x16x32_bf16(af[mf], bf[nt], acc[mf][nt], 0, 0, 0);
    };

    load_ab(0, af0, bf0);
    for (int kc = 0; kc < 16; kc += 2) {
        load_ab(kc + 1, af1, bf1);
        do_mfma(af0, bf0);
        load_ab((kc + 2) & 15, af0, bf0);   // phantom wrap reload on last iter
        do_mfma(af1, bf1);
    }

    int part = j0 >> 9;            // 0=q,1=k,2=v
    int h = (j0 & 511) >> 6;
    int b_ = m0 >> 11, tloc = m0 & (T - 1);
    int bh = b_ * NH + h;
    float bcol[4];
    #pragma unroll
    for (int nt = 0; nt < 4; ++nt) bcol[nt] = bias[j0 + nt * 16 + lm];

    if (part == 2) {
        // V' = w*V; LDS [dh][key]; C-layout r-runs contiguous -> b64 writes
        float wv[4][4];
        #pragma unroll
        for (int mf = 0; mf < 4; ++mf)
            #pragma unroll
            for (int r = 0; r < 4; ++r)
                wv[mf][r] = wexp[b_ * T + tloc + mf * 16 + quad * 4 + r];
        #pragma unroll
        for (int mf = 0; mf < 4; ++mf)
            #pragma unroll
            for (int nt = 0; nt < 4; ++nt) {
                uint2 pw;
                pw.x = pack_bf16_pair((acc[mf][nt][0] + bcol[nt]) * wv[mf][0],
                                      (acc[mf][nt][1] + bcol[nt]) * wv[mf][1]);
                pw.y = pack_bf16_pair((acc[mf][nt][2] + bcol[nt]) * wv[mf][2],
                                      (acc[mf][nt][3] + bcol[nt]) * wv[mf][3]);
                *(uint2*)&Ls[wave][nt * 16 + lm][mf * 16 + quad * 4] = pw;
            }
        #pragma unroll
        for (int nt = 0; nt < 4; ++nt)
            #pragma unroll
            for (int kk = 0; kk < 2; ++kk) {
                bf16x8 fr = *(const bf16x8*)&Ls[wave][nt * 16 + lm][kk * 32 + quad * 8];
                size_t chunk = ((((size_t)bh * 32 + (tloc >> 6)) * 2 + kk) * 5) + nt;
                *(bf16x8*)(vfrag + chunk * 512 + lane * 8) = fr;
            }
        // w-column (nt=4) of vfrag: lm==0 lanes carry w, rest zero.
        // (wfrag_fill fused here -- each part-2 wave uniquely owns (bh,t64,kk).)
        #pragma unroll
        for (int kk = 0; kk < 2; ++kk) {
            size_t chunk = ((((size_t)bh * 32 + (tloc >> 6)) * 2 + kk) * 5) + 4;
            uint4 pk = {0u, 0u, 0u, 0u};
            if (lm == 0) {
                const float* wp = wexp + b_ * T + tloc + kk * 32 + quad * 8;
                unsigned short vv[8];
                #pragma unroll
                for (int e = 0; e < 8; ++e) vv[e] = f2bf(wp[e]);
                pk = *(uint4*)vv;
            }
            *(uint4*)(vfrag + chunk * 512 + (size_t)lane * 8) = pk;
        }
    } else {
        // LDS [token][dh]; scalar b16 writes (one-time), b128 frag reads
        float scale = (part == 0) ? QSCALE : 1.0f;
        #pragma unroll
        for (int mf = 0; mf < 4; ++mf)
            #pragma unroll
            for (int nt = 0; nt < 4; ++nt)
                #pragma unroll
                for (int r = 0; r < 4; ++r)
                    Ls[wave][mf * 16 + quad * 4 + r][nt * 16 + lm] =
                        f2bf((acc[mf][nt][r] + bcol[nt]) * scale);
        if (part == 0) {
            #pragma unroll
            for (int mf = 0; mf < 4; ++mf)
                #pragma unroll
                for (int kk = 0; kk < 2; ++kk) {
                    bf16x8 fr = *(const bf16x8*)&Ls[wave][mf * 16 + lm][kk * 32 + quad * 8];
                    size_t chunk = ((size_t)bh * 128 + (tloc >> 4) + mf) * 2 + kk;
                    *(bf16x8*)(qfrag + chunk * 512 + lane * 8) = fr;
                }
        } else {
            #pragma unroll
            for (int nta = 0; nta < 4; ++nta)
                #pragma unroll
                for (int kk = 0; kk < 2; ++kk) {
                    bf16x8 fr = *(const bf16x8*)&Ls[wave][lm * 4 + nta][kk * 32 + quad * 8];
                    size_t chunk = ((((size_t)bh * 32 + (tloc >> 6)) * 2 + kk) * 4) + nta;
                    *(bf16x8*)(kfrag + chunk * 512 + lane * 8) = fr;
                }
        }
    }
}

// ---------------- Kernel 3: flash attention, pipelined P round-trip ---------
// (R3 structure: 48.3us, MfmaUtil ~32, VALUBusy ~45, no spill)
__global__ __launch_bounds__(256, 2) void attn_mfma(
    const unsigned short* __restrict__ qfrag, const unsigned short* __restrict__ kfrag,
    const unsigned short* __restrict__ vfrag, const float* __restrict__ kpmf,
    float* __restrict__ S)
{
    __shared__ __align__(16) unsigned short Ps[4][2][64][72];  // per-wave, dbuf
    __shared__ float Lx[2][2][64];                             // [qh][ks][row]
    int g = blockIdx.x;
    int bh = g & 31, q0 = (g >> 5) * 128;
    int tid = threadIdx.x, wave = tid >> 6, lane = tid & 63;
    int quad = lane >> 4, lm = lane & 15;
    int qh = wave >> 1, ks = wave & 1;
    int qbase = q0 + qh * 64;
    int b_ = bh >> 3, h = bh & 7;

    bf16x8 qf[4][2];
    int t16b = (qbase >> 4);
    #pragma unroll
    for (int mf = 0; mf < 4; ++mf)
        #pragma unroll
        for (int kk = 0; kk < 2; ++kk)
            qf[mf][kk] = *(const bf16x8*)(qfrag +
                (((size_t)(bh * 128 + t16b + mf) * 2 + kk) * 64 + lane) * 8);

    f32x4 accO[4][4], accL[4];
    #pragma unroll
    for (int mf = 0; mf < 4; ++mf) {
        #pragma unroll
        for (int nt = 0; nt < 4; ++nt) accO[mf][nt] = (f32x4){0.f,0.f,0.f,0.f};
        accL[mf] = (f32x4){0.f,0.f,0.f,0.f};
    }

    const unsigned short* kb = kfrag + (size_t)bh * 32 * 8 * 512 + (size_t)lane * 8;
    const unsigned short* vb = vfrag + (size_t)bh * 32 * 10 * 512 + (size_t)lane * 8;
    int t0k = ks * 16;   // wave's 16 key-tiles

    bf16x8 kf[4][2];
    auto load_k = [&](int t64) {
        const unsigned short* p = kb + (size_t)t64 * 8 * 512;
        #pragma unroll
        for (int kk = 0; kk < 2; ++kk)
            #pragma unroll
            for (int nt = 0; nt < 4; ++nt)
                kf[nt][kk] = *(const bf16x8*)(p + ((size_t)kk * 4 + nt) * 512);
    };
    auto load_v = [&](int t64, bf16x8 (&vf)[5][2]) {
        const unsigned short* p = vb + (size_t)t64 * 10 * 512;
        #pragma unroll
        for (int kk = 0; kk < 2; ++kk)
            #pragma unroll
            for (int nt = 0; nt < 5; ++nt)
                vf[nt][kk] = *(const bf16x8*)(p + ((size_t)kk * 5 + nt) * 512);
    };
    auto load_p = [&](int buf, bf16x8 (&pf)[4][2]) {
        #pragma unroll
        for (int mf = 0; mf < 4; ++mf)
            #pragma unroll
            for (int kk = 0; kk < 2; ++kk)
                pf[mf][kk] = *(const bf16x8*)&Ps[wave][buf][mf * 16 + lm][kk * 32 + quad * 8];
    };
    // QK(current kf) -> exp2 -> write Ps[buf]
    auto qk_exp = [&](int buf) {
        #pragma unroll
        for (int mf = 0; mf < 4; ++mf) {
            f32x4 s[4];
            __builtin_amdgcn_s_setprio(1);
            #pragma unroll
            for (int nt = 0; nt < 4; ++nt) {
                f32x4 t0 = (f32x4){0.f,0.f,0.f,0.f};
                t0 = __builtin_amdgcn_mfma_f32_16x16x32_bf16(qf[mf][0], kf[nt][0], t0, 0, 0, 0);
                t0 = __builtin_amdgcn_mfma_f32_16x16x32_bf16(qf[mf][1], kf[nt][1], t0, 0, 0, 0);
                s[nt] = t0;
            }
            __builtin_amdgcn_s_setprio(0);
            int rowb = mf * 16 + quad * 4;
            #pragma unroll
            for (int r = 0; r < 4; ++r) {
                float p0 = __builtin_amdgcn_exp2f(s[0][r]);
                float p1 = __builtin_amdgcn_exp2f(s[1][r]);
                float p2 = __builtin_amdgcn_exp2f(s[2][r]);
                float p3 = __builtin_amdgcn_exp2f(s[3][r]);
                uint2 pw;
                pw.x = pack_bf16_pair(p0, p1);
                pw.y = pack_bf16_pair(p2, p3);
                *(uint2*)&Ps[wave][buf][rowb + r][lm * 4] = pw;
            }
        }
    };
    auto pv = [&](bf16x8 (&pf)[4][2], bf16x8 (&vf)[5][2]) {
        __builtin_amdgcn_s_setprio(1);
        #pragma unroll
        for (int mf = 0; mf < 4; ++mf) {
            #pragma unroll
            for (int nt = 0; nt < 4; ++nt) {
                accO[mf][nt] = __builtin_amdgcn_mfma_f32_16x16x32_bf16(pf[mf][0], vf[nt][0], accO[mf][nt], 0, 0, 0);
                accO[mf][nt] = __builtin_amdgcn_mfma_f32_16x16x32_bf16(pf[mf][1], vf[nt][1], accO[mf][nt], 0, 0, 0);
            }
            accL[mf] = __builtin_amdgcn_mfma_f32_16x16x32_bf16(pf[mf][0], vf[4][0], accL[mf], 0, 0, 0);
            accL[mf] = __builtin_amdgcn_mfma_f32_16x16x32_bf16(pf[mf][1], vf[4][1], accL[mf], 0, 0, 0);
        }
        __builtin_amdgcn_s_setprio(0);
    };

    // software pipeline, one tile deep: PV(t-1) overlaps QK/exp(t)
    load_k(t0k);
    qk_exp(0);                       // tile 0 -> Ps buf 0
    load_k(t0k + 1);
    for (int t = 1; t < 16; ++t) {
        bf16x8 pf[4][2], vf[5][2];
        load_p((t - 1) & 1, pf);     // LDS latency hides under QK(t)
        load_v(t0k + t - 1, vf);     // L2 latency hides under QK+exp(t)
        qk_exp(t & 1);
        load_k(t0k + ((t + 1) & 15));  // phantom wrap reload on last iter
        pv(pf, vf);
    }
    {   // epilogue: PV of tile 15
        bf16x8 pf[4][2], vf[5][2];
        load_p(1, pf);
        load_v(t0k + 15, vf);
        pv(pf, vf);
    }

    // exchange partial l across the key-half pair (one barrier total)
    if (lm == 0) {
        #pragma unroll
        for (int mf = 0; mf < 4; ++mf)
            #pragma unroll
            for (int r = 0; r < 4; ++r)
                Lx[qh][ks][mf * 16 + quad * 4 + r] = accL[mf][r];
    }
    __syncthreads();

    // fused masked pooling with full l
    float pooled[4] = {0.f, 0.f, 0.f, 0.f};
    #pragma unroll
    for (int mf = 0; mf < 4; ++mf)
        #pragma unroll
        for (int r = 0; r < 4; ++r) {
            int rloc = mf * 16 + quad * 4 + r;
            float l = Lx[qh][0][rloc] + Lx[qh][1][rloc];
            float w = (1.0f - kpmf[b_ * T + qbase + rloc]) / l;
            #pragma unroll
            for (int nt = 0; nt < 4; ++nt) pooled[nt] += accO[mf][nt][r] * w;
        }
    #pragma unroll
    for (int nt = 0; nt < 4; ++nt) {
        pooled[nt] += __shfl_xor(pooled[nt], 16, 64);
        pooled[nt] += __shfl_xor(pooled[nt], 32, 64);
    }
    if (quad == 0) {
        #pragma unroll
        for (int nt = 0; nt < 4; ++nt)
            atomicAdd(&S[b_ * D + h * DH + nt * 16 + lm], pooled[nt]);
    }
}

// ---------------- Kernel 4: out-projection of pooled vector + bias ----------
__global__ __launch_bounds__(256) void out_kernel(
    const float* __restrict__ S, const float* __restrict__ kpmf,
    const float* __restrict__ Wo, const float* __restrict__ bo,
    float* __restrict__ out)
{
    __shared__ float Sl[512];
    __shared__ float cs[4];
    __shared__ float pr[4][64];
    int b_ = blockIdx.x >> 3;
    int cg = blockIdx.x & 7;
    int tid = threadIdx.x;
    int col = tid & 63, kq = tid >> 6;
    Sl[tid] = S[b_ * D + tid];
    Sl[tid + 256] = S[b_ * D + tid + 256];
    const float* kp = kpmf + b_ * T;
    float c = 0.f;
    for (int t = tid; t < T; t += 256) c += kp[t];
    #pragma unroll
    for (int o = 32; o; o >>= 1) c += __shfl_xor(c, o, 64);
    if ((tid & 63) == 0) cs[tid >> 6] = c;
    __syncthreads();
    float masked = cs[0] + cs[1] + cs[2] + cs[3];
    float cnt = (float)T - masked;
    float inv = 1.0f / fmaxf(cnt, 1.0f);

    int d = cg * 64 + col;
    const float4* wr4 = (const float4*)(Wo + (size_t)d * D + kq * 128);
    float dot = 0.f;
    #pragma unroll 8
    for (int i = 0; i < 32; ++i) {
        float4 w4 = wr4[i];
        int kbase = kq * 128 + i * 4;
        dot += Sl[kbase + 0] * w4.x + Sl[kbase + 1] * w4.y +
               Sl[kbase + 2] * w4.z + Sl[kbase + 3] * w4.w;
    }
    pr[kq][col] = dot;
    __syncthreads();
    if (kq == 0) {
        float tot = pr[0][col] + pr[1][col] + pr[2][col] + pr[3][col];
        out[b_ * D + d] = (tot + bo[d] * cnt) * inv;
    }
}

extern "C" void kernel_launch(void* const* d_in, const int* in_sizes, int n_in,
                              void* d_out, int out_size, void* d_ws, size_t ws_size,
                              hipStream_t stream) {
    const float* embs   = (const float*)d_in[0];
    const float* labels = (const float*)d_in[1];
    const float* ln_g   = (const float*)d_in[2];
    const float* ln_b   = (const float*)d_in[3];
    const float* ipw    = (const float*)d_in[4];
    const float* ipb    = (const float*)d_in[5];
    const float* ow     = (const float*)d_in[6];
    const float* obb    = (const float*)d_in[7];
    const float* alpha  = (const float*)d_in[8];
    const float* beta   = (const float*)d_in[9];
    float* out = (float*)d_out;

    unsigned short* xfrag  = (unsigned short*)d_ws;          // 8192*512
    unsigned short* wbfrag = xfrag + (size_t)NTOK * D;       // 1536*512
    unsigned short* qfrag  = wbfrag + (size_t)3 * D * D;     // 8192*512
    unsigned short* kfrag  = qfrag + (size_t)NTOK * D;       // 8192*512
    unsigned short* vfrag  = kfrag + (size_t)NTOK * D;       // 32*32*2*5*512
    float* wexp = (float*)(vfrag + (size_t)32 * 32 * 2 * 5 * 512);  // 8192
    float* kpmf = wexp + NTOK;                               // 8192
    float* S    = kpmf + NTOK;                               // 2048

    prep_kernel<<<609, 256, 0, stream>>>(embs, labels, ln_g, ln_b, alpha, beta,
                                         ipw, xfrag, wexp, kpmf, wbfrag, S);
    dim3 gq(NTOK / 128, (3 * D) / 128);
    qkv_mfma<<<gq, 256, 0, stream>>>(xfrag, wbfrag, ipb, wexp, qfrag, kfrag, vfrag);
    attn_mfma<<<32 * (T / 128), 256, 0, stream>>>(qfrag, kfrag, vfrag, kpmf, S);
    out_kernel<<<NB * 8, 256, 0, stream>>>(S, kpmf, ow, obb, out);
}